// Round 1
// baseline (23241.846 us; speedup 1.0000x reference)
//
#include <hip/hip_runtime.h>

#define NB 64
#define NT 1000
#define NH 512
#define NI 32
#define NO 32
#define ALPHA 0.05f
#define NOISE_STD 0.05f

// One workgroup per batch element. 1024 threads:
//   - matvec r@wrec split-K x2: thread (j = tid&511, half = tid>>9) does 256 MACs
//   - out projection: 32 segments x 16 rows, reduced via LDS
// h, r live in LDS; whole T-loop inside one launch.
__global__ __launch_bounds__(1024, 1) void rnn_seq_kernel(
    const float* __restrict__ x, const float* __restrict__ noise,
    const float* __restrict__ wi, const float* __restrict__ wrec,
    const float* __restrict__ wout, const float* __restrict__ bias,
    const float* __restrict__ g, const float* __restrict__ tM,
    const float* __restrict__ h0, float* __restrict__ out)
{
    const int bidx = blockIdx.x;
    const int tid  = threadIdx.x;
    const int j    = tid & (NH - 1);
    const int half = tid >> 9;

    __shared__ float hs[NH];        // current hidden state
    __shared__ float rs[NH];        // relu(h)
    __shared__ float accb[NH];      // K-half-1 partial sums
    __shared__ float xt[NI];        // current x_t
    __shared__ float red[32][NO + 1]; // out-projection partials (+1 pad)

    float a_inv = 0.f, gj = 0.f, bj = 0.f;
    if (tid < NH) {
        hs[tid] = h0[tid];
        a_inv   = ALPHA / tM[tid];   // alpha * tM^-1
        gj      = g[tid];
        bj      = bias[tid];
    }
    __syncthreads();

    const int k   = tid & (NO - 1);
    const int seg = tid >> 5;        // 0..31, 16 rows each

    for (int t = 0; t < NT; ++t) {
        // r = relu(h); load x_t with spare threads
        if (tid < NH) rs[tid] = fmaxf(hs[tid], 0.f);
        if (t < NT - 1 && tid >= NH && tid < NH + NI)
            xt[tid - NH] = x[((size_t)bidx * NT + t) * NI + (tid - NH)];
        __syncthreads();

        // prefetch noise early (HBM latency hides under the matvec)
        float nv = 0.f;
        if (t < NT - 1 && tid < NH)
            nv = noise[((size_t)bidx * NT + t) * NH + tid];

        // output projection: out[b,t,:] = relu(h_t) @ wout
        {
            float p = 0.f;
            const int base = seg * 16;
            #pragma unroll
            for (int m = 0; m < 16; ++m)
                p += rs[base + m] * wout[(base + m) * NO + k];
            red[seg][k] = p;
        }

        // recurrent matvec: acc_j = sum_i r_i * wrec[i][j]  (split K x2)
        float acc = 0.f;
        if (t < NT - 1) {
            const float* wr = wrec + ((size_t)half * 256) * NH + j;
            const int rbase = half * 256;
            #pragma unroll 16
            for (int i = 0; i < 256; ++i)
                acc += rs[rbase + i] * wr[(size_t)i * NH];
            if (half) accb[j] = acc;
        }
        __syncthreads();

        // h update (threads 0..511 own one j each)
        if (t < NT - 1 && tid < NH) {
            float accf = acc + accb[j];
            float xw = 0.f;
            #pragma unroll
            for (int i = 0; i < NI; ++i)
                xw += xt[i] * wi[i * NH + j];
            float h = hs[j];
            hs[j] = h + NOISE_STD * nv + a_inv * (-h + gj * accf + bj + xw);
        }

        // reduce + write output row t
        if (tid < NO) {
            float s = 0.f;
            #pragma unroll
            for (int sg = 0; sg < 32; ++sg) s += red[sg][tid];
            out[((size_t)bidx * NT + t) * NO + tid] = s;
        }
        __syncthreads();
    }
}

extern "C" void kernel_launch(void* const* d_in, const int* in_sizes, int n_in,
                              void* d_out, int out_size, void* d_ws, size_t ws_size,
                              hipStream_t stream) {
    const float* x     = (const float*)d_in[0];
    const float* noise = (const float*)d_in[1];
    const float* wi    = (const float*)d_in[2];
    const float* wrec  = (const float*)d_in[3];
    const float* wout  = (const float*)d_in[4];
    const float* bias  = (const float*)d_in[5];
    const float* g     = (const float*)d_in[6];
    const float* tM    = (const float*)d_in[7];
    const float* h0    = (const float*)d_in[8];
    float* out = (float*)d_out;

    rnn_seq_kernel<<<NB, 1024, 0, stream>>>(x, noise, wi, wrec, wout, bias, g, tM, h0, out);
}

// Round 2
// 7397.903 us; speedup vs baseline: 3.1417x; 3.1417x over previous
//
#include <hip/hip_runtime.h>
#include <hip/hip_fp16.h>

#define NB 64
#define NT 1000
#define NH 512
#define NI 32
#define NO 32
#define ALPHA 0.05f
#define NOISE_STD 0.05f

typedef unsigned int uint32;
typedef __attribute__((ext_vector_type(2))) _Float16 half2v;

__device__ __forceinline__ float dot2f(uint32 a, uint32 b, float c) {
#if __has_builtin(__builtin_amdgcn_fdot2)
    return __builtin_amdgcn_fdot2(__builtin_bit_cast(half2v, a),
                                  __builtin_bit_cast(half2v, b), c, false);
#else
    half2v av = __builtin_bit_cast(half2v, a);
    half2v bv = __builtin_bit_cast(half2v, b);
    return c + (float)av[0] * (float)bv[0] + (float)av[1] * (float)bv[1];
#endif
}

// --------- precompute c[b][t][j] = NOISE_STD*noise + (ALPHA/tM_j)*(x_t @ wi)_j  (f16) ---------
__global__ __launch_bounds__(512) void precompute_c_kernel(
    const float* __restrict__ x, const float* __restrict__ noise,
    const float* __restrict__ wi, const float* __restrict__ tM,
    __half* __restrict__ cbuf)
{
    const int bt = blockIdx.x;      // b*NT + t
    const int j = threadIdx.x;
    __shared__ float xs[NI];
    if (j < NI) xs[j] = x[(size_t)bt * NI + j];
    __syncthreads();
    const float a_inv = ALPHA * (1.0f / tM[j]);
    const float nv = noise[(size_t)bt * NH + j];
    float xw = 0.f;
    #pragma unroll
    for (int i = 0; i < NI; ++i) xw += xs[i] * wi[i * NH + j];
    cbuf[(size_t)bt * NH + j] = __float2half(NOISE_STD * nv + a_inv * xw);
}

// --------- main: 4 WGs per batch (column split), LDS-resident f16 wrec slice ---------
__global__ __launch_bounds__(512, 1) void rnn_split_kernel(
    const float* __restrict__ wrec, const float* __restrict__ wout,
    const float* __restrict__ bias, const float* __restrict__ g,
    const float* __restrict__ tM, const float* __restrict__ h0,
    const __half* __restrict__ cbuf, unsigned short* __restrict__ wsr,
    uint32* __restrict__ ctr, float* __restrict__ out, int useC,
    const float* __restrict__ noise, const float* __restrict__ wi,
    const float* __restrict__ x)
{
    __shared__ __align__(16) unsigned short wt[128 * 512];  // wrecT slice, swizzled (131 KB)
    __shared__ __align__(16) unsigned short wo16[8 * 512];  // wout slice [o][r] (8 KB)
    __shared__ __align__(16) unsigned short r16[NH];        // current full r (f16)
    __shared__ float red[128][4];
    __shared__ float redo[8][8];
    __shared__ float xs[NI];

    const int bid = blockIdx.x;
    const int tid = threadIdx.x;
    // group the 4 slices of one batch onto the same XCD (round-robin heuristic; correctness
    // does not depend on it — agent-scope ops are used throughout)
    const int b = ((bid >> 5) << 3) | (bid & 7);
    const int k = (bid >> 3) & 3;

    // ---- stage wrec column-slice (cols [128k,128k+128)) as f16, XOR-swizzled ----
    {
        const int cl = tid & 127;
        const int q4 = tid >> 7;
        #pragma unroll 4
        for (int ii = 0; ii < 128; ++ii) {
            const int i = (ii << 2) | q4;                    // row index
            float w = wrec[(size_t)i * NH + 128 * k + cl];   // coalesced over cl
            wt[cl * 512 + 8 * ((i >> 3) ^ (cl & 15)) + (i & 7)] =
                __half_as_ushort(__float2half(w));
        }
        // wout slice: cols [8k, 8k+8) -> wo16[o][r]
        const int r = tid;
        #pragma unroll
        for (int o = 0; o < 8; ++o)
            wo16[o * 512 + r] = __half_as_ushort(__float2half(wout[r * NO + 8 * k + o]));
        if (tid < 256) ((uint32*)r16)[tid] = 0u;
    }

    float h = 0.f, a_inv = 0.f, gj = 0.f, bj = 0.f;
    const int jl = tid & 127, q = tid >> 7;
    const int jc = 128 * k + jl;
    if (tid < 128) {
        h = h0[jc];
        a_inv = ALPHA * (1.0f / tM[jc]);
        gj = g[jc];
        bj = bias[jc];
    }
    __syncthreads();

    const int o_ = tid & 7, seg = tid >> 3;
    const int wv_ = tid >> 6, ln = tid & 63;

    uint32* ctrb = ctr + b * 32;                        // 128B line per batch
    unsigned short* wsr_base = wsr + (size_t)b * 2 * NH;

    for (int t = 0; t < NT; ++t) {
        unsigned short* wp = wsr_base + (t & 1) * NH;
        // phase 1: publish r(t) = relu(h) for own columns (agent-scope, bypasses L1/L2)
        float rv_own = fmaxf(h, 0.f);
        {
            int hb = (int)__half_as_ushort(__float2half(rv_own));
            int pb = __shfl_xor(hb, 1, 64);              // partner half
            if (tid < 128 && (tid & 1) == 0) {
                uint32 val = (uint32)(unsigned short)hb | ((uint32)(unsigned short)pb << 16);
                __hip_atomic_store((uint32*)wp + ((128 * k + jl) >> 1), val,
                                   __ATOMIC_RELAXED, __HIP_MEMORY_SCOPE_AGENT);
            }
        }
        asm volatile("s_waitcnt vmcnt(0)" ::: "memory");
        if (tid < 128 && (tid & 63) == 0)
            __hip_atomic_fetch_add(ctrb, 64u, __ATOMIC_RELEASE, __HIP_MEMORY_SCOPE_AGENT);

        // prefetch per-step additive term (latency hides under outproj + poll)
        float cval = 0.f;
        if (useC) {
            if (tid < 128) cval = __half2float(cbuf[((size_t)b * NT + t) * NH + jc]);
        } else {
            if (tid < 128) cval = NOISE_STD * noise[((size_t)b * NT + t) * NH + jc];
        }

        // phase 2: out-projection for step t-1 (r16 still holds r(t-1)); hides in poll window
        {
            float oa = 0.f;
            const uint32* wop = (const uint32*)(wo16 + o_ * 512);
            const uint32* rp = (const uint32*)r16;
            #pragma unroll
            for (int c4 = 0; c4 < 4; ++c4)
                oa = dot2f(wop[seg * 4 + c4], rp[seg * 4 + c4], oa);
            oa += __shfl_xor(oa, 8, 64);
            oa += __shfl_xor(oa, 16, 64);
            oa += __shfl_xor(oa, 32, 64);
            if (ln < 8) redo[wv_][ln] = oa;
            __syncthreads();
            if (tid < 8 && t > 0) {
                float s = 0.f;
                #pragma unroll
                for (int w2 = 0; w2 < 8; ++w2) s += redo[w2][tid];
                out[((size_t)b * NT + (t - 1)) * NO + 8 * k + tid] = s;
            }
        }

        // phase 3: gate — wait for all 4 slices of this batch
        if (tid == 0) {
            while (__hip_atomic_load(ctrb, __ATOMIC_ACQUIRE, __HIP_MEMORY_SCOPE_AGENT)
                   < 512u * (uint32)(t + 1))
                __builtin_amdgcn_s_sleep(1);
        }
        __syncthreads();

        // phase 4: fetch full r(t) into LDS (+ stage x_t for no-C path)
        if (tid < 256)
            ((uint32*)r16)[tid] = __hip_atomic_load((const uint32*)wp + tid,
                                    __ATOMIC_RELAXED, __HIP_MEMORY_SCOPE_AGENT);
        if (!useC && tid < NI) xs[tid] = x[((size_t)b * NT + t) * NI + tid];
        __syncthreads();

        // phase 5: matvec — thread (jl,q): rows [128q,128q+128) of column jc
        {
            float acc = 0.f;
            const uint32* rp = (const uint32*)r16;
            #pragma unroll
            for (int mm = 0; mm < 16; ++mm) {
                const int islot = q * 16 + mm;
                const uint4 wv4 = *(const uint4*)(wt + jl * 512 + 8 * (islot ^ (jl & 15)));
                const uint4 rv4 = *(const uint4*)(rp + islot * 4);
                acc = dot2f(wv4.x, rv4.x, acc);
                acc = dot2f(wv4.y, rv4.y, acc);
                acc = dot2f(wv4.z, rv4.z, acc);
                acc = dot2f(wv4.w, rv4.w, acc);
            }
            red[jl][q] = acc;
        }
        __syncthreads();

        // phase 6: h update (owners only)
        if (tid < 128 && t < NT - 1) {
            float hsum = red[jl][0] + red[jl][1] + red[jl][2] + red[jl][3];
            if (!useC) {
                float xw = 0.f;
                #pragma unroll
                for (int i = 0; i < NI; ++i) xw += xs[i] * wi[i * NH + jc];
                cval += a_inv * xw;
            }
            h = h + cval + a_inv * (-h + gj * hsum + bj);
        }
    }

    // final output row t = NT-1 (r16 holds r(NT-1))
    {
        float oa = 0.f;
        const uint32* wop = (const uint32*)(wo16 + o_ * 512);
        const uint32* rp = (const uint32*)r16;
        #pragma unroll
        for (int c4 = 0; c4 < 4; ++c4)
            oa = dot2f(wop[seg * 4 + c4], rp[seg * 4 + c4], oa);
        oa += __shfl_xor(oa, 8, 64);
        oa += __shfl_xor(oa, 16, 64);
        oa += __shfl_xor(oa, 32, 64);
        if (ln < 8) redo[wv_][ln] = oa;
        __syncthreads();
        if (tid < 8) {
            float s = 0.f;
            #pragma unroll
            for (int w2 = 0; w2 < 8; ++w2) s += redo[w2][tid];
            out[((size_t)b * NT + (NT - 1)) * NO + 8 * k + tid] = s;
        }
    }
}

// --------- round-1 fallback (used only if ws is too small) ---------
__global__ __launch_bounds__(1024, 1) void rnn_seq_kernel(
    const float* __restrict__ x, const float* __restrict__ noise,
    const float* __restrict__ wi, const float* __restrict__ wrec,
    const float* __restrict__ wout, const float* __restrict__ bias,
    const float* __restrict__ g, const float* __restrict__ tM,
    const float* __restrict__ h0, float* __restrict__ out)
{
    const int bidx = blockIdx.x;
    const int tid  = threadIdx.x;
    const int j    = tid & (NH - 1);
    const int half = tid >> 9;

    __shared__ float hs[NH];
    __shared__ float rs[NH];
    __shared__ float accb[NH];
    __shared__ float xt[NI];
    __shared__ float red[32][NO + 1];

    float a_inv = 0.f, gj = 0.f, bj = 0.f;
    if (tid < NH) {
        hs[tid] = h0[tid];
        a_inv   = ALPHA / tM[tid];
        gj      = g[tid];
        bj      = bias[tid];
    }
    __syncthreads();

    const int k   = tid & (NO - 1);
    const int seg = tid >> 5;

    for (int t = 0; t < NT; ++t) {
        if (tid < NH) rs[tid] = fmaxf(hs[tid], 0.f);
        if (t < NT - 1 && tid >= NH && tid < NH + NI)
            xt[tid - NH] = x[((size_t)bidx * NT + t) * NI + (tid - NH)];
        __syncthreads();

        float nv = 0.f;
        if (t < NT - 1 && tid < NH)
            nv = noise[((size_t)bidx * NT + t) * NH + tid];

        {
            float p = 0.f;
            const int base = seg * 16;
            #pragma unroll
            for (int m = 0; m < 16; ++m)
                p += rs[base + m] * wout[(base + m) * NO + k];
            red[seg][k] = p;
        }

        float acc = 0.f;
        if (t < NT - 1) {
            const float* wr = wrec + ((size_t)half * 256) * NH + j;
            const int rbase = half * 256;
            #pragma unroll 16
            for (int i = 0; i < 256; ++i)
                acc += rs[rbase + i] * wr[(size_t)i * NH];
            if (half) accb[j] = acc;
        }
        __syncthreads();

        if (t < NT - 1 && tid < NH) {
            float accf = acc + accb[j];
            float xw = 0.f;
            #pragma unroll
            for (int i = 0; i < NI; ++i)
                xw += xt[i] * wi[i * NH + j];
            float hv = hs[j];
            hs[j] = hv + NOISE_STD * nv + a_inv * (-hv + gj * accf + bj + xw);
        }

        if (tid < NO) {
            float s = 0.f;
            #pragma unroll
            for (int sg = 0; sg < 32; ++sg) s += red[sg][tid];
            out[((size_t)bidx * NT + t) * NO + tid] = s;
        }
        __syncthreads();
    }
}

extern "C" void kernel_launch(void* const* d_in, const int* in_sizes, int n_in,
                              void* d_out, int out_size, void* d_ws, size_t ws_size,
                              hipStream_t stream) {
    const float* x     = (const float*)d_in[0];
    const float* noise = (const float*)d_in[1];
    const float* wi    = (const float*)d_in[2];
    const float* wrec  = (const float*)d_in[3];
    const float* wout  = (const float*)d_in[4];
    const float* bias  = (const float*)d_in[5];
    const float* g     = (const float*)d_in[6];
    const float* tM    = (const float*)d_in[7];
    const float* h0    = (const float*)d_in[8];
    float* out = (float*)d_out;

    const size_t cb_bytes  = (size_t)NB * NT * NH * 2;   // 65,536,000
    const size_t wsr_bytes = (size_t)NB * 2 * NH * 2;    // 131,072
    const size_t ctr_bytes = 8192;

    char* wsb = (char*)d_ws;
    if (ws_size >= cb_bytes + wsr_bytes + ctr_bytes) {
        __half* cbuf = (__half*)wsb;
        unsigned short* wsr = (unsigned short*)(wsb + cb_bytes);
        uint32* ctr = (uint32*)(wsb + cb_bytes + wsr_bytes);
        hipMemsetAsync(ctr, 0, ctr_bytes, stream);
        precompute_c_kernel<<<NB * NT, 512, 0, stream>>>(x, noise, wi, tM, cbuf);
        rnn_split_kernel<<<NB * 4, 512, 0, stream>>>(wrec, wout, bias, g, tM, h0,
                                                     cbuf, wsr, ctr, out, 1,
                                                     noise, wi, x);
    } else if (ws_size >= wsr_bytes + ctr_bytes) {
        unsigned short* wsr = (unsigned short*)wsb;
        uint32* ctr = (uint32*)(wsb + wsr_bytes);
        hipMemsetAsync(ctr, 0, ctr_bytes, stream);
        rnn_split_kernel<<<NB * 4, 512, 0, stream>>>(wrec, wout, bias, g, tM, h0,
                                                     (const __half*)nullptr, wsr, ctr, out, 0,
                                                     noise, wi, x);
    } else {
        rnn_seq_kernel<<<NB, 1024, 0, stream>>>(x, noise, wi, wrec, wout, bias, g, tM, h0, out);
    }
}

// Round 3
// 1654.756 us; speedup vs baseline: 14.0455x; 4.4707x over previous
//
#include <hip/hip_runtime.h>
#include <hip/hip_fp16.h>

#define NB 64
#define NT 1000
#define NH 512
#define NI 32
#define NO 32
#define ALPHA 0.05f
#define NOISE_STD 0.05f

typedef unsigned int uint32;
typedef __attribute__((ext_vector_type(2))) _Float16 half2v;

__device__ __forceinline__ float dot2f(uint32 a, uint32 b, float c) {
#if __has_builtin(__builtin_amdgcn_fdot2)
    return __builtin_amdgcn_fdot2(__builtin_bit_cast(half2v, a),
                                  __builtin_bit_cast(half2v, b), c, false);
#else
    half2v av = __builtin_bit_cast(half2v, a);
    half2v bv = __builtin_bit_cast(half2v, b);
    return c + (float)av[0] * (float)bv[0] + (float)av[1] * (float)bv[1];
#endif
}

// --------- precompute c[b][t][j] = NOISE_STD*noise + (ALPHA/tM_j)*(x_t @ wi)_j  (f16) ---------
__global__ __launch_bounds__(512) void precompute_c_kernel(
    const float* __restrict__ x, const float* __restrict__ noise,
    const float* __restrict__ wi, const float* __restrict__ tM,
    __half* __restrict__ cbuf)
{
    const int bt = blockIdx.x;      // b*NT + t
    const int j = threadIdx.x;
    __shared__ float xs[NI];
    if (j < NI) xs[j] = x[(size_t)bt * NI + j];
    __syncthreads();
    const float a_inv = ALPHA * (1.0f / tM[j]);
    const float nv = noise[(size_t)bt * NH + j];
    float xw = 0.f;
    #pragma unroll
    for (int i = 0; i < NI; ++i) xw += xs[i] * wi[i * NH + j];
    cbuf[(size_t)bt * NH + j] = __float2half(NOISE_STD * nv + a_inv * xw);
}

// --------- main: 4 WGs per batch (column split), self-tagged r exchange ---------
// wsr[b] : 2 parity slots x 512 dwords, each dword = (t<<16) | f16bits(r_j)
__global__ __launch_bounds__(512, 1) void rnn_split_kernel(
    const float* __restrict__ wrec, const float* __restrict__ wout,
    const float* __restrict__ bias, const float* __restrict__ g,
    const float* __restrict__ tM, const float* __restrict__ h0,
    const __half* __restrict__ cbuf, uint32* __restrict__ wsr,
    float* __restrict__ out)
{
    __shared__ __align__(16) unsigned short wt[128 * 512];  // wrecT slice, swizzled (131 KB)
    __shared__ __align__(16) unsigned short r16[NH];        // current full r (f16)
    __shared__ float red[128][5];                           // matvec partials (+1 pad)
    __shared__ float redo[8][9];                            // outproj partials (+1 pad)

    const int bid = blockIdx.x;
    const int tid = threadIdx.x;
    // put the 4 slices of one batch on the same XCD (perf heuristic only)
    const int b = ((bid >> 5) << 3) | (bid & 7);
    const int k = (bid >> 3) & 3;

    // ---- stage wrec column-slice (cols [128k,128k+128)) as f16, XOR-swizzled ----
    {
        const int cl = tid & 127;
        const int q4 = tid >> 7;
        #pragma unroll 4
        for (int ii = 0; ii < 128; ++ii) {
            const int i = (ii << 2) | q4;                    // row index
            float w = wrec[(size_t)i * NH + 128 * k + cl];   // coalesced over cl
            wt[cl * 512 + 8 * ((i >> 3) ^ (cl & 15)) + (i & 7)] =
                __half_as_ushort(__float2half(w));
        }
    }

    const int jl = tid & 127, q = tid >> 7;
    const int jc = 128 * k + jl;
    float h = 0.f, a_inv = 0.f, gj = 0.f, bj = 0.f;
    if (tid < 128) {
        h = h0[jc];
        a_inv = ALPHA * (1.0f / tM[jc]);
        gj = g[jc];
        bj = bias[jc];
    }

    // ---- out-projection weights live in registers (thread-invariant indices) ----
    const int o_ = tid & 7, seg = tid >> 3;    // seg 0..63, 8 r-values each
    uint32 wreg[4];
    #pragma unroll
    for (int c4 = 0; c4 < 4; ++c4) {
        float w0 = wout[(size_t)(seg * 8 + 2 * c4)     * NO + 8 * k + o_];
        float w1 = wout[(size_t)(seg * 8 + 2 * c4 + 1) * NO + 8 * k + o_];
        __half2 hp = __floats2half2_rn(w0, w1);
        wreg[c4] = *(uint32*)&hp;
    }
    __syncthreads();

    const int wv_ = tid >> 6, ln = tid & 63;
    uint32* wsrb = wsr + b * 1024;             // 2 slots x 512 dwords

    for (int t = 0; t < NT; ++t) {
        uint32* wp = wsrb + (t & 1) * 512;

        // phase 1: publish own r(t) — single relaxed agent-scope dword, self-tagged
        if (tid < 128) {
            float rv = fmaxf(h, 0.f);
            uint32 val = ((uint32)t << 16) | (uint32)__half_as_ushort(__float2half(rv));
            __hip_atomic_store(wp + jc, val, __ATOMIC_RELAXED, __HIP_MEMORY_SCOPE_AGENT);
        }

        // prefetch per-step additive term (latency hides under outproj + poll)
        float cval = 0.f;
        if (tid < 128) cval = __half2float(cbuf[((size_t)b * NT + t) * NH + jc]);

        // phase 2: out-projection for step t-1 (r16 holds r(t-1)); hides publish latency
        {
            float oa = 0.f;
            const uint32* rp = (const uint32*)r16;
            #pragma unroll
            for (int c4 = 0; c4 < 4; ++c4)
                oa = dot2f(wreg[c4], rp[seg * 4 + c4], oa);   // rp: wave broadcast
            oa += __shfl_xor(oa, 8, 64);
            oa += __shfl_xor(oa, 16, 64);
            oa += __shfl_xor(oa, 32, 64);
            if (ln < 8) redo[wv_][ln] = oa;
        }
        __syncthreads();
        if (tid < 8 && t > 0) {
            float s = 0.f;
            #pragma unroll
            for (int w2 = 0; w2 < 8; ++w2) s += redo[w2][tid];
            out[((size_t)b * NT + (t - 1)) * NO + 8 * k + tid] = s;
        }

        // phase 3: poll own dword until tag == t, deposit into LDS
        {
            const uint32 tg = (uint32)t;
            uint32 v;
            do {
                v = __hip_atomic_load(wp + tid, __ATOMIC_RELAXED, __HIP_MEMORY_SCOPE_AGENT);
            } while ((v >> 16) != tg);
            r16[tid] = (unsigned short)(v & 0xffffu);
        }
        __syncthreads();

        // phase 4: matvec — thread (jl,q): rows [128q,128q+128) of column jc
        if (t < NT - 1) {
            float acc = 0.f;
            const uint32* rp = (const uint32*)r16;
            #pragma unroll
            for (int mm = 0; mm < 16; ++mm) {
                const int islot = q * 16 + mm;
                const uint4 wv4 = *(const uint4*)(wt + jl * 512 + 8 * (islot ^ (jl & 15)));
                const uint4 rv4 = *(const uint4*)(rp + islot * 4);
                acc = dot2f(wv4.x, rv4.x, acc);
                acc = dot2f(wv4.y, rv4.y, acc);
                acc = dot2f(wv4.z, rv4.z, acc);
                acc = dot2f(wv4.w, rv4.w, acc);
            }
            red[jl][q] = acc;
        }
        __syncthreads();

        // phase 5: h update (owners only)
        if (tid < 128 && t < NT - 1) {
            float hsum = red[jl][0] + red[jl][1] + red[jl][2] + red[jl][3];
            h = h + cval + a_inv * (-h + gj * hsum + bj);
        }
    }

    // final output row t = NT-1 (r16 holds r(NT-1))
    {
        float oa = 0.f;
        const uint32* rp = (const uint32*)r16;
        #pragma unroll
        for (int c4 = 0; c4 < 4; ++c4)
            oa = dot2f(wreg[c4], rp[seg * 4 + c4], oa);
        oa += __shfl_xor(oa, 8, 64);
        oa += __shfl_xor(oa, 16, 64);
        oa += __shfl_xor(oa, 32, 64);
        if (ln < 8) redo[wv_][ln] = oa;
        __syncthreads();
        if (tid < 8) {
            float s = 0.f;
            #pragma unroll
            for (int w2 = 0; w2 < 8; ++w2) s += redo[w2][tid];
            out[((size_t)b * NT + (NT - 1)) * NO + 8 * k + tid] = s;
        }
    }
}

// --------- round-1 fallback (used only if ws is too small) ---------
__global__ __launch_bounds__(1024, 1) void rnn_seq_kernel(
    const float* __restrict__ x, const float* __restrict__ noise,
    const float* __restrict__ wi, const float* __restrict__ wrec,
    const float* __restrict__ wout, const float* __restrict__ bias,
    const float* __restrict__ g, const float* __restrict__ tM,
    const float* __restrict__ h0, float* __restrict__ out)
{
    const int bidx = blockIdx.x;
    const int tid  = threadIdx.x;
    const int j    = tid & (NH - 1);
    const int half = tid >> 9;

    __shared__ float hs[NH];
    __shared__ float rs[NH];
    __shared__ float accb[NH];
    __shared__ float xt[NI];
    __shared__ float red[32][NO + 1];

    float a_inv = 0.f, gj = 0.f, bj = 0.f;
    if (tid < NH) {
        hs[tid] = h0[tid];
        a_inv   = ALPHA / tM[tid];
        gj      = g[tid];
        bj      = bias[tid];
    }
    __syncthreads();

    const int k   = tid & (NO - 1);
    const int seg = tid >> 5;

    for (int t = 0; t < NT; ++t) {
        if (tid < NH) rs[tid] = fmaxf(hs[tid], 0.f);
        if (t < NT - 1 && tid >= NH && tid < NH + NI)
            xt[tid - NH] = x[((size_t)bidx * NT + t) * NI + (tid - NH)];
        __syncthreads();

        float nv = 0.f;
        if (t < NT - 1 && tid < NH)
            nv = noise[((size_t)bidx * NT + t) * NH + tid];

        {
            float p = 0.f;
            const int base = seg * 16;
            #pragma unroll
            for (int m = 0; m < 16; ++m)
                p += rs[base + m] * wout[(base + m) * NO + k];
            red[seg][k] = p;
        }

        float acc = 0.f;
        if (t < NT - 1) {
            const float* wr = wrec + ((size_t)half * 256) * NH + j;
            const int rbase = half * 256;
            #pragma unroll 16
            for (int i = 0; i < 256; ++i)
                acc += rs[rbase + i] * wr[(size_t)i * NH];
            if (half) accb[j] = acc;
        }
        __syncthreads();

        if (t < NT - 1 && tid < NH) {
            float accf = acc + accb[j];
            float xw = 0.f;
            #pragma unroll
            for (int i = 0; i < NI; ++i)
                xw += xt[i] * wi[i * NH + j];
            float hv = hs[j];
            hs[j] = hv + NOISE_STD * nv + a_inv * (-hv + gj * accf + bj + xw);
        }

        if (tid < NO) {
            float s = 0.f;
            #pragma unroll
            for (int sg = 0; sg < 32; ++sg) s += red[sg][tid];
            out[((size_t)bidx * NT + t) * NO + tid] = s;
        }
        __syncthreads();
    }
}

extern "C" void kernel_launch(void* const* d_in, const int* in_sizes, int n_in,
                              void* d_out, int out_size, void* d_ws, size_t ws_size,
                              hipStream_t stream) {
    const float* x     = (const float*)d_in[0];
    const float* noise = (const float*)d_in[1];
    const float* wi    = (const float*)d_in[2];
    const float* wrec  = (const float*)d_in[3];
    const float* wout  = (const float*)d_in[4];
    const float* bias  = (const float*)d_in[5];
    const float* g     = (const float*)d_in[6];
    const float* tM    = (const float*)d_in[7];
    const float* h0    = (const float*)d_in[8];
    float* out = (float*)d_out;

    const size_t cb_bytes  = (size_t)NB * NT * NH * 2;     // 65,536,000
    const size_t wsr_bytes = (size_t)NB * 1024 * 4;        // 262,144

    char* wsb = (char*)d_ws;
    if (ws_size >= cb_bytes + wsr_bytes) {
        __half* cbuf = (__half*)wsb;
        uint32* wsr = (uint32*)(wsb + cb_bytes);
        // neutralize stale/uninit tags (0xAAAA tag can never equal t<1000)
        hipMemsetAsync(wsr, 0xAA, wsr_bytes, stream);
        precompute_c_kernel<<<NB * NT, 512, 0, stream>>>(x, noise, wi, tM, cbuf);
        rnn_split_kernel<<<NB * 4, 512, 0, stream>>>(wrec, wout, bias, g, tM, h0,
                                                     cbuf, wsr, out);
    } else {
        rnn_seq_kernel<<<NB, 1024, 0, stream>>>(x, noise, wi, wrec, wout, bias, g, tM, h0, out);
    }
}